// Round 11
// baseline (61.649 us; speedup 1.0000x reference)
//
#include <hip/hip_runtime.h>
#include <hip/hip_bf16.h>
#include <math.h>

#define NROWS 32768
#define DDIM  1024
#define NEXP  64
#define TAU   2e-4f
#define EPSF  1e-9f
#define CAPMAX 8192
#define NSHARD 8
#define NCH   32                 // chunks of BK=32 fp32 k (2 kc each)

typedef __attribute__((ext_vector_type(8)))  short  short8;
typedef __attribute__((ext_vector_type(16))) float  f32x16;
typedef __attribute__((address_space(3))) unsigned int       lds_u32;
typedef __attribute__((address_space(1))) const unsigned int g_u32;

// stable greater-than: value desc, index asc on ties (matches lax.top_k)
__device__ __forceinline__ bool gt_(float a, int ea, float b, int eb)
{ return a > b || (a == b && ea < eb); }

// split f into bf16 hi (RTNE) + bf16 lo (RTNE of exact residual).
__device__ __forceinline__ void cvt_hl(float f, short& h, short& l)
{
    __hip_bfloat16 hb = __float2bfloat16(f);
    float r = f - __bfloat162float(hb);
    __hip_bfloat16 lb = __float2bfloat16(r);
    h = *reinterpret_cast<short*>(&hb);
    l = *reinterpret_cast<short*>(&lb);
}

// ---------------------------------------------------------------------------
// Pack gate_w ONCE into per-lane MFMA B-fragment order, bf16 hi+lo
// (fragment lane-mapping HW-verified R5-R10). Block 0 zeroes shards + cnt.
// wp bytes: ((kc*2+g)*2+pr)*1024 + lane*16  (kc 0..63, g expert-half, pr hi/lo)
// ---------------------------------------------------------------------------
__global__ void wpack_kernel(const float* __restrict__ gw,
                             unsigned short* __restrict__ wp,
                             float* __restrict__ shard,
                             int* __restrict__ cnt)
{
    if (blockIdx.x == 0) {
        shard[threadIdx.x]       = 0.0f;
        shard[256 + threadIdx.x] = 0.0f;
        if (threadIdx.x == 0) *cnt = 0;
    }
    const int kc = blockIdx.x;              // 0..63
    const int t  = threadIdx.x;             // 256
    const int lane = t & 63, g = (t >> 6) & 1, pr = t >> 7;
    const int e = g * 32 + (lane & 31);
    const int k = kc * 16 + (lane >> 5) * 8;
    float4 f0 = *reinterpret_cast<const float4*>(gw + (size_t)e * DDIM + k);
    float4 f1 = *reinterpret_cast<const float4*>(gw + (size_t)e * DDIM + k + 4);
    float f[8] = {f0.x, f0.y, f0.z, f0.w, f1.x, f1.y, f1.z, f1.w};
    short8 o;
    #pragma unroll
    for (int j = 0; j < 8; ++j) {
        short hh, ll;
        cvt_hl(f[j], hh, ll);
        o[j] = pr ? ll : hh;
    }
    *reinterpret_cast<short8*>(wp + ((size_t)((kc * 2 + g) * 2 + pr) * 64 + lane) * 8) = o;
}

// ---------------------------------------------------------------------------
// Main: x via 4-buffer global_load_lds pipeline (depth 3, counted vmcnt);
// B via ROTATING REGISTERS loaded 1 chunk ahead from L2-resident wp (no LDS).
// grid 512 x 256 thr; block = 64 rows x 64 experts; wave (wm,g) owns the
// 32x32 quadrant rows[wm*32..) x experts[g*32..), FULL K (no split-K).
// Per iteration i (chunk = BK=32 fp32 k = 2 kc):
//   load B regs for chunk i+1 (4 short8)        <- before STAGE (count order)
//   STAGE(i+3): 2 global_load_lds(16B)/thread   (x swizzled)
//   sched_barrier; s_waitcnt vmcnt(8); s_barrier; sched_barrier
//   compute i (2 kc x {2 f4 ds_read + hw-cvt + 3 MFMA}) using B(i) regs
//   sched_barrier; s_barrier; sched_barrier
// In-order vmcnt: steady 8 = stage(i+2)2 + B(i+1)4 + stage(i+3)2;
// prologue i=0: 6; tail: 6 / 4 / 0.  LDS 32 KB -> 4 blocks/CU (16 waves).
// ---------------------------------------------------------------------------
__global__ __launch_bounds__(256, 4) void moe_main(
    const float* __restrict__ x, const unsigned short* __restrict__ wp,
    float* __restrict__ out, float* __restrict__ shard,
    int* __restrict__ cnt, int* __restrict__ list, int cap)
{
    extern __shared__ char smem[];          // 32 KB: x 4 x 8 KB

    const int t = threadIdx.x;
    const int wave = t >> 6, lane = t & 63;
    const int wm = wave & 1, g = wave >> 1;
    const int l31 = lane & 31, l5 = lane >> 5;
    const int row0 = blockIdx.x * 64;
    const int arow = wm * 32 + l31;         // this lane's x row within tile
    const int xr   = (arow & 7) << 4;       // read-side swizzle

    f32x16 acc;
    #pragma unroll
    for (int r = 0; r < 16; ++r) acc[r] = 0.0f;

    // staging map (swizzle precomputed per thread, 2 slots)
    int srow[2], scol[2];
    #pragma unroll
    for (int q = 0; q < 2; ++q) {
        int d = q * 4096 + t * 16;
        srow[q] = d >> 7;
        scol[q] = (d & 127) ^ ((srow[q] & 7) << 4);
    }

    // B-fragment base for this wave's expert half g (chunk c, kcl, pr):
    //   wp + (((c*2+kcl)*2+g)*2+pr)*1024 + lane*16 bytes
    const char* wqb = (const char*)wp + (size_t)g * 2048 + (size_t)lane * 16;

    #define STAGE(c_) do {                                                       \
        const char* xs0_ = (const char*)x + (size_t)row0 * 4096 + (size_t)(c_) * 128; \
        const int xb_ = ((c_) & 3) * 8192;                                       \
        _Pragma("unroll")                                                        \
        for (int q_ = 0; q_ < 2; ++q_) {                                         \
            int d_ = q_ * 4096 + t * 16;                                         \
            const char* xsrc_ = xs0_ + (size_t)srow[q_] * 4096 + scol[q_];       \
            __builtin_amdgcn_global_load_lds((g_u32*)xsrc_,                      \
                (lds_u32*)(smem + xb_ + d_), 16, 0, 0);                          \
        }                                                                        \
    } while (0)

    #define BLOAD(dst0, dst1, dst2, dst3, c_) do {                               \
        const char* b_ = wqb + (size_t)(c_) * 8192;                              \
        dst0 = *reinterpret_cast<const short8*>(b_);                             \
        dst1 = *reinterpret_cast<const short8*>(b_ + 1024);                      \
        dst2 = *reinterpret_cast<const short8*>(b_ + 4096);                      \
        dst3 = *reinterpret_cast<const short8*>(b_ + 5120);                      \
    } while (0)

    short8 Bc0, Bc1, Bc2, Bc3, Bn0, Bn1, Bn2, Bn3;

    // prologue: 3 x-chunks in flight, B(0) in regs
    STAGE(0); STAGE(1); STAGE(2);
    BLOAD(Bc0, Bc1, Bc2, Bc3, 0);

    for (int i = 0; i < NCH; ++i) {
        if (i < NCH - 1) BLOAD(Bn0, Bn1, Bn2, Bn3, i + 1);
        if (i < NCH - 3) STAGE(i + 3);
        __builtin_amdgcn_sched_barrier(0);
        if (i == 0)               { asm volatile("s_waitcnt vmcnt(6)" ::: "memory"); }
        else if (i < NCH - 3)     { asm volatile("s_waitcnt vmcnt(8)" ::: "memory"); }
        else if (i == NCH - 3)    { asm volatile("s_waitcnt vmcnt(6)" ::: "memory"); }
        else if (i == NCH - 2)    { asm volatile("s_waitcnt vmcnt(4)" ::: "memory"); }
        else                      { asm volatile("s_waitcnt vmcnt(0)" ::: "memory"); }
        __builtin_amdgcn_s_barrier();
        __builtin_amdgcn_sched_barrier(0);

        const int xb = (i & 3) * 8192;
        #pragma unroll
        for (int kcl = 0; kcl < 2; ++kcl) {
            const int cb = kcl * 64 + l5 * 32;          // within-row byte base
            const char* xrow = smem + xb + arow * 128;
            float4 f0 = *reinterpret_cast<const float4*>(xrow + (cb ^ xr));
            float4 f1 = *reinterpret_cast<const float4*>(xrow + ((cb + 16) ^ xr));
            float f[8] = {f0.x, f0.y, f0.z, f0.w, f1.x, f1.y, f1.z, f1.w};
            short8 ah, al;
            #pragma unroll
            for (int jj = 0; jj < 8; ++jj) {
                short hh, ll;
                cvt_hl(f[jj], hh, ll);
                ah[jj] = hh; al[jj] = ll;
            }
            short8 bh = kcl ? Bc2 : Bc0;
            short8 bl = kcl ? Bc3 : Bc1;
            acc = __builtin_amdgcn_mfma_f32_32x32x16_bf16(ah, bh, acc, 0, 0, 0);
            acc = __builtin_amdgcn_mfma_f32_32x32x16_bf16(al, bh, acc, 0, 0, 0);
            acc = __builtin_amdgcn_mfma_f32_32x32x16_bf16(ah, bl, acc, 0, 0, 0);
        }
        Bc0 = Bn0; Bc1 = Bn1; Bc2 = Bn2; Bc3 = Bn3;
        __builtin_amdgcn_sched_barrier(0);
        __builtin_amdgcn_s_barrier();       // protect buf (i+1)&3 overwrite
        __builtin_amdgcn_sched_barrier(0);
    }
    #undef STAGE
    #undef BLOAD

    // ---- logits -> LDS [64][68] f32 (C layout verified R5-R10) ------------
    float* lgs = reinterpret_cast<float*>(smem);
    __syncthreads();
    #pragma unroll
    for (int r = 0; r < 16; ++r) {          // col=lane&31, row=(r&3)+8*(r>>2)+4*l5
        const int lrow = wm * 32 + (r & 3) + 8 * (r >> 2) + 4 * l5;
        lgs[lrow * 68 + g * 32 + l31] = acc[r];
    }
    __syncthreads();

    // ---- row epilogue: 4 threads per row, 16 experts each (verified R5+) --
    const int erow = t >> 2, q = t & 3;
    float L[16];
    #pragma unroll
    for (int i = 0; i < 4; ++i) {
        float4 v = *reinterpret_cast<const float4*>(lgs + erow * 68 + q * 16 + i * 4);
        L[4*i] = v.x; L[4*i+1] = v.y; L[4*i+2] = v.z; L[4*i+3] = v.w;
    }
    float v1 = -3.4e38f, v2 = -3.4e38f, v3 = -3.4e38f;
    int   e1 = 1 << 30,  e2 = 1 << 30,  e3 = 1 << 30;
    #pragma unroll
    for (int i = 0; i < 16; ++i) {
        float v = L[i]; int e = q * 16 + i;
        if      (gt_(v, e, v1, e1)) { v3=v2; e3=e2; v2=v1; e2=e1; v1=v; e1=e; }
        else if (gt_(v, e, v2, e2)) { v3=v2; e3=e2; v2=v; e2=e; }
        else if (gt_(v, e, v3, e3)) { v3=v; e3=e; }
    }
    #pragma unroll
    for (int m = 1; m <= 2; m <<= 1) {      // merge the row's 4 lanes
        float o1 = __shfl_xor(v1, m), o2 = __shfl_xor(v2, m), o3 = __shfl_xor(v3, m);
        int  oe1 = __shfl_xor(e1, m), oe2 = __shfl_xor(e2, m), oe3 = __shfl_xor(e3, m);
        float n1, n2, n3; int m1, m2, m3;
        if (gt_(v1, e1, o1, oe1)) {
            n1 = v1; m1 = e1;
            if (gt_(v2, e2, o1, oe1)) {
                n2 = v2; m2 = e2;
                if (gt_(v3, e3, o1, oe1)) { n3 = v3; m3 = e3; } else { n3 = o1; m3 = oe1; }
            } else {
                n2 = o1; m2 = oe1;
                if (gt_(v2, e2, o2, oe2)) { n3 = v2; m3 = e2; } else { n3 = o2; m3 = oe2; }
            }
        } else {
            n1 = o1; m1 = oe1;
            if (gt_(o2, oe2, v1, e1)) {
                n2 = o2; m2 = oe2;
                if (gt_(o3, oe3, v1, e1)) { n3 = o3; m3 = oe3; } else { n3 = v1; m3 = e1; }
            } else {
                n2 = v1; m2 = e1;
                if (gt_(o2, oe2, v2, e2)) { n3 = o2; m3 = oe2; } else { n3 = v2; m3 = e2; }
            }
        }
        v1 = n1; e1 = m1; v2 = n2; e2 = m2; v3 = n3; e3 = m3;
    }
    float pr[16], sl = 0.0f;
    #pragma unroll
    for (int i = 0; i < 16; ++i) { pr[i] = expf(L[i] - v1); sl += pr[i]; }
    float S = sl;
    S += __shfl_xor(S, 1); S += __shfl_xor(S, 2);
    const float invS = 1.0f / S;
    #pragma unroll
    for (int i = 0; i < 16; ++i) pr[i] *= invS;
    // per-expert partial sums across this wave's 16 rows
    #pragma unroll
    for (int m = 4; m <= 32; m <<= 1)
        #pragma unroll
        for (int i = 0; i < 16; ++i) pr[i] += __shfl_xor(pr[i], m);
    float* auxred = lgs + 64 * 68;          // 4 waves x 64 experts
    if (lane < 4) {
        #pragma unroll
        for (int i = 0; i < 16; ++i) auxred[wave * 64 + q * 16 + i] = pr[i];
    }
    if (q == 0) {
        const float p1 = invS;              // exp(v1-v1)*invS
        const float p2 = expf(v2 - v1) * invS;
        const float dn = p1 + p2 + EPSF;
        const int r = row0 + erow;
        out[2 * r]                 = p1 / dn;
        out[2 * r + 1]             = p2 / dn;
        out[2 * NROWS + 2 * r]     = (float)e1;
        out[2 * NROWS + 2 * r + 1] = (float)e2;
        if (cap > 0 && (v1 - v2 < TAU || v2 - v3 < TAU)) {
            int pos = atomicAdd(cnt, 1);
            if (pos < cap) list[pos] = r;
        }
    }
    __syncthreads();
    if (t < 64) {
        float s = auxred[t] + auxred[64 + t] + auxred[128 + t] + auxred[192 + t];
        atomicAdd(&shard[(blockIdx.x & (NSHARD - 1)) * 64 + t], s);
    }
}

// ---------------------------------------------------------------------------
// Finalize: block 0 sums 8 aux shards -> aux loss; blocks 1..64 repair
// flagged rows with exact fp32 logits.
// ---------------------------------------------------------------------------
__global__ __launch_bounds__(256) void finalize_kernel(
    const float* __restrict__ x, const float* __restrict__ gw,
    float* __restrict__ out, const float* __restrict__ shard,
    const int* __restrict__ cnt, const int* __restrict__ list, int cap)
{
    if (blockIdx.x == 0) {
        const int tt = threadIdx.x;
        if (tt < 64) {
            float m = 0.0f;
            #pragma unroll
            for (int s = 0; s < NSHARD; ++s) m += shard[s * 64 + tt];
            m *= (1.0f / (float)NROWS);
            float v = m * logf(m + EPSF);
            #pragma unroll
            for (int k = 1; k <= 32; k <<= 1) v += __shfl_xor(v, k);
            if (tt == 0) out[4 * NROWS] = v;
        }
        return;
    }
    __shared__ float lg[64];
    const int n = (cap > 0) ? min(*cnt, cap) : 0;
    const int tt = threadIdx.x, e = tt >> 2, part = tt & 3;
    for (int j = (int)blockIdx.x - 1; j < n; j += 64) {
        const int row = list[j];
        const float* xrp = x  + (size_t)row * DDIM + part * 256;
        const float* wrp = gw + (size_t)e   * DDIM + part * 256;
        float a = 0.0f;
        #pragma unroll 8
        for (int kk = 0; kk < 64; ++kk) {
            float4 xv = *reinterpret_cast<const float4*>(xrp + kk * 4);
            float4 wv = *reinterpret_cast<const float4*>(wrp + kk * 4);
            a += xv.x * wv.x + xv.y * wv.y + xv.z * wv.z + xv.w * wv.w;
        }
        a += __shfl_xor(a, 1); a += __shfl_xor(a, 2);
        if (part == 0) lg[e] = a;
        __syncthreads();
        if (tt < 4) {
            const int q = tt;
            float v1 = -3.4e38f, v2 = -3.4e38f; int e1 = 1 << 30, e2 = 1 << 30;
            float Lr[16];
            #pragma unroll
            for (int i = 0; i < 16; ++i) {
                float v = Lr[i] = lg[q * 16 + i]; int ee = q * 16 + i;
                if      (gt_(v, ee, v1, e1)) { v2 = v1; e2 = e1; v1 = v; e1 = ee; }
                else if (gt_(v, ee, v2, e2)) { v2 = v; e2 = ee; }
            }
            #pragma unroll
            for (int m = 1; m <= 2; m <<= 1) {
                float o1 = __shfl_xor(v1, m), o2 = __shfl_xor(v2, m);
                int  oe1 = __shfl_xor(e1, m), oe2 = __shfl_xor(e2, m);
                float n1, n2; int m1, m2;
                if (gt_(v1, e1, o1, oe1)) {
                    n1 = v1; m1 = e1;
                    if (gt_(v2, e2, o1, oe1)) { n2 = v2; m2 = e2; } else { n2 = o1; m2 = oe1; }
                } else {
                    n1 = o1; m1 = oe1;
                    if (gt_(o2, oe2, v1, e1)) { n2 = o2; m2 = oe2; } else { n2 = v1; m2 = e1; }
                }
                v1 = n1; e1 = m1; v2 = n2; e2 = m2;
            }
            float s = 0.0f;
            #pragma unroll
            for (int i = 0; i < 16; ++i) s += expf(Lr[i] - v1);
            s += __shfl_xor(s, 1); s += __shfl_xor(s, 2);
            if (q == 0) {
                const float invS = 1.0f / s;
                const float p1 = invS, p2 = expf(v2 - v1) * invS;
                const float dn = p1 + p2 + EPSF;
                out[2 * row]                 = p1 / dn;
                out[2 * row + 1]             = p2 / dn;
                out[2 * NROWS + 2 * row]     = (float)e1;
                out[2 * NROWS + 2 * row + 1] = (float)e2;
            }
        }
        __syncthreads();
    }
}

extern "C" void kernel_launch(void* const* d_in, const int* in_sizes, int n_in,
                              void* d_out, int out_size, void* d_ws, size_t ws_size,
                              hipStream_t stream)
{
    const float* x  = (const float*)d_in[0];
    const float* gw = (const float*)d_in[1];
    float* out      = (float*)d_out;

    // d_ws layout: [wp 256KB][shard 2KB][cnt 4B pad->256B][list ...]
    unsigned short* wp = (unsigned short*)d_ws;
    float* shard   = (float*)((char*)d_ws + 262144);
    int*   cnt     = (int*)((char*)d_ws + 264192);
    int*   list    = (int*)((char*)d_ws + 264448);
    int cap = 0;
    if (ws_size >= 264448 + 4096) {
        size_t avail = (ws_size - 264448) / sizeof(int);
        cap = (avail > CAPMAX) ? CAPMAX : (int)avail;
    }

    hipLaunchKernelGGL(wpack_kernel, dim3(64), dim3(256), 0, stream,
                       gw, wp, shard, cnt);
    hipLaunchKernelGGL(moe_main, dim3(NROWS / 64), dim3(256), 32768, stream,
                       x, wp, out, shard, cnt, list, cap);
    hipLaunchKernelGGL(finalize_kernel, dim3(65), dim3(256), 0, stream,
                       x, gw, out, shard, cnt, list, cap);
}

// Round 12
// 61.359 us; speedup vs baseline: 1.0047x; 1.0047x over previous
//
#include <hip/hip_runtime.h>
#include <hip/hip_bf16.h>
#include <math.h>

#define NROWS 32768
#define DDIM  1024
#define NEXP  64
#define TAU   2e-4f
#define EPSF  1e-9f
#define CAPMAX 8192
#define NSHARD 8
#define NCH   16                 // chunks of BK=64 fp32 k (4 kc each)

typedef __attribute__((ext_vector_type(8)))  short  short8;
typedef __attribute__((ext_vector_type(16))) float  f32x16;
typedef __attribute__((address_space(3))) unsigned int       lds_u32;
typedef __attribute__((address_space(1))) const unsigned int g_u32;

// stable greater-than: value desc, index asc on ties (matches lax.top_k)
__device__ __forceinline__ bool gt_(float a, int ea, float b, int eb)
{ return a > b || (a == b && ea < eb); }

// split f into bf16 hi (RTNE) + bf16 lo (RTNE of exact residual).
__device__ __forceinline__ void cvt_hl(float f, short& h, short& l)
{
    __hip_bfloat16 hb = __float2bfloat16(f);
    float r = f - __bfloat162float(hb);
    __hip_bfloat16 lb = __float2bfloat16(r);
    h = *reinterpret_cast<short*>(&hb);
    l = *reinterpret_cast<short*>(&lb);
}

// ---------------------------------------------------------------------------
// Pack gate_w ONCE into per-lane MFMA B-fragment order, bf16 hi+lo
// (fragment lane-mapping HW-verified R5-R11). Block 0 zeroes shards + cnt.
// wp bytes: kc*4096 + g*2048 + pr*1024 + lane*16  (kc 0..63, g half, pr hi/lo)
// ---------------------------------------------------------------------------
__global__ void wpack_kernel(const float* __restrict__ gw,
                             unsigned short* __restrict__ wp,
                             float* __restrict__ shard,
                             int* __restrict__ cnt)
{
    if (blockIdx.x == 0) {
        shard[threadIdx.x]       = 0.0f;
        shard[256 + threadIdx.x] = 0.0f;
        if (threadIdx.x == 0) *cnt = 0;
    }
    const int kc = blockIdx.x;              // 0..63
    const int t  = threadIdx.x;             // 256
    const int lane = t & 63, g = (t >> 6) & 1, pr = t >> 7;
    const int e = g * 32 + (lane & 31);
    const int k = kc * 16 + (lane >> 5) * 8;
    float4 f0 = *reinterpret_cast<const float4*>(gw + (size_t)e * DDIM + k);
    float4 f1 = *reinterpret_cast<const float4*>(gw + (size_t)e * DDIM + k + 4);
    float f[8] = {f0.x, f0.y, f0.z, f0.w, f1.x, f1.y, f1.z, f1.w};
    short8 o;
    #pragma unroll
    for (int j = 0; j < 8; ++j) {
        short hh, ll;
        cvt_hl(f[j], hh, ll);
        o[j] = pr ? ll : hh;
    }
    *reinterpret_cast<short8*>(wp + ((size_t)((kc * 2 + g) * 2 + pr) * 64 + lane) * 8) = o;
}

// ---------------------------------------------------------------------------
// Main: grid 1024 x 128 thr (2 waves). Block = 32 rows x 64 experts; wave g
// owns rows 0..31 x experts [g*32, g*32+32), FULL K. 4 independent blocks/CU.
// Chunk = BK=64 fp32 k (4 kc); NCH=16 -> half the barrier count of R11.
// x: 4-buffer global_load_lds pipeline, depth 3 (counted vmcnt).
// B: rotating registers loaded 1 chunk ahead from L2-resident wp.
// Per iteration i:  BLOAD(i+1)[8 ld] ; STAGE(i+3)[4 gl_lds] ;
//   sched_barrier ; s_waitcnt vmcnt(N) ; s_barrier ; sched_barrier ;
//   compute i (4 kc x {2 f4 ds_read + hw-cvt + 3 MFMA}) ;
//   sched_barrier ; s_barrier ; sched_barrier
// In-order vmcnt (S=4, B=8 events): i==0 ->12 ; 1..12 ->16 ; 13->12 ;
// 14->8 ; 15->0.  x swizzle both-sides (256-B rows): byte ^= ((row&7)<<4).
// ---------------------------------------------------------------------------
__global__ __launch_bounds__(128, 2) void moe_main(
    const float* __restrict__ x, const unsigned short* __restrict__ wp,
    float* __restrict__ out, float* __restrict__ shard,
    int* __restrict__ cnt, int* __restrict__ list, int cap)
{
    extern __shared__ char smem[];          // 32 KB: x 4 x 8 KB

    const int t = threadIdx.x;              // 0..127
    const int g = t >> 6;                   // wave = expert half
    const int lane = t & 63;
    const int l31 = lane & 31, l5 = lane >> 5;
    const int row0 = blockIdx.x * 32;
    const int arow = l31;                   // lane's x row within 32-row tile
    const int xr   = (arow & 7) << 4;       // read-side swizzle

    f32x16 acc;
    #pragma unroll
    for (int r = 0; r < 16; ++r) acc[r] = 0.0f;

    // staging map: 4 slots, d = q*2048 + t*16 covers [32 rows][256 B] linear
    int srow[4], scol[4];
    #pragma unroll
    for (int q = 0; q < 4; ++q) {
        int d = q * 2048 + t * 16;
        srow[q] = d >> 8;
        scol[q] = (d & 255) ^ ((srow[q] & 7) << 4);
    }

    const char* wqb = (const char*)wp + (size_t)g * 2048 + (size_t)lane * 16;

    #define STAGE(c_) do {                                                       \
        const char* xs0_ = (const char*)x + (size_t)row0 * 4096 + (size_t)(c_) * 256; \
        const int xb_ = ((c_) & 3) * 8192;                                       \
        _Pragma("unroll")                                                        \
        for (int q_ = 0; q_ < 4; ++q_) {                                         \
            int d_ = q_ * 2048 + t * 16;                                         \
            const char* xsrc_ = xs0_ + (size_t)srow[q_] * 4096 + scol[q_];       \
            __builtin_amdgcn_global_load_lds((g_u32*)xsrc_,                      \
                (lds_u32*)(smem + xb_ + d_), 16, 0, 0);                          \
        }                                                                        \
    } while (0)

    #define BLOAD(dst_, c_) do {                                                 \
        _Pragma("unroll")                                                        \
        for (int kcl_ = 0; kcl_ < 4; ++kcl_) {                                   \
            const char* b_ = wqb + (size_t)((c_) * 4 + kcl_) * 4096;             \
            dst_[kcl_][0] = *reinterpret_cast<const short8*>(b_);                \
            dst_[kcl_][1] = *reinterpret_cast<const short8*>(b_ + 1024);         \
        }                                                                        \
    } while (0)

    short8 Bc[4][2], Bn[4][2];

    // prologue: 3 x-chunks in flight, then B(0)
    STAGE(0); STAGE(1); STAGE(2);
    BLOAD(Bc, 0);

    for (int i = 0; i < NCH; ++i) {
        if (i < NCH - 1) BLOAD(Bn, i + 1);
        if (i < NCH - 3) STAGE(i + 3);
        __builtin_amdgcn_sched_barrier(0);
        if (i == 0)               { asm volatile("s_waitcnt vmcnt(12)" ::: "memory"); }
        else if (i < NCH - 3)     { asm volatile("s_waitcnt vmcnt(16)" ::: "memory"); }
        else if (i == NCH - 3)    { asm volatile("s_waitcnt vmcnt(12)" ::: "memory"); }
        else if (i == NCH - 2)    { asm volatile("s_waitcnt vmcnt(8)" ::: "memory"); }
        else                      { asm volatile("s_waitcnt vmcnt(0)" ::: "memory"); }
        __builtin_amdgcn_s_barrier();
        __builtin_amdgcn_sched_barrier(0);

        const int xb = (i & 3) * 8192;
        const char* xrow = smem + xb + arow * 256;
        #pragma unroll
        for (int kcl = 0; kcl < 4; ++kcl) {
            const int cb = kcl * 64 + l5 * 32;          // within-row byte base
            float4 f0 = *reinterpret_cast<const float4*>(xrow + (cb ^ xr));
            float4 f1 = *reinterpret_cast<const float4*>(xrow + ((cb + 16) ^ xr));
            float f[8] = {f0.x, f0.y, f0.z, f0.w, f1.x, f1.y, f1.z, f1.w};
            short8 ah, al;
            #pragma unroll
            for (int jj = 0; jj < 8; ++jj) {
                short hh, ll;
                cvt_hl(f[jj], hh, ll);
                ah[jj] = hh; al[jj] = ll;
            }
            acc = __builtin_amdgcn_mfma_f32_32x32x16_bf16(ah, Bc[kcl][0], acc, 0, 0, 0);
            acc = __builtin_amdgcn_mfma_f32_32x32x16_bf16(al, Bc[kcl][0], acc, 0, 0, 0);
            acc = __builtin_amdgcn_mfma_f32_32x32x16_bf16(ah, Bc[kcl][1], acc, 0, 0, 0);
        }
        #pragma unroll
        for (int kcl = 0; kcl < 4; ++kcl) {
            Bc[kcl][0] = Bn[kcl][0];
            Bc[kcl][1] = Bn[kcl][1];
        }
        __builtin_amdgcn_sched_barrier(0);
        __builtin_amdgcn_s_barrier();       // protect buf (i+1)&3 overwrite
        __builtin_amdgcn_sched_barrier(0);
    }
    #undef STAGE
    #undef BLOAD

    // ---- logits -> LDS [32][68] f32 (C layout verified R5-R11) ------------
    float* lgs = reinterpret_cast<float*>(smem);
    __syncthreads();
    #pragma unroll
    for (int r = 0; r < 16; ++r) {          // col=lane&31, row=(r&3)+8*(r>>2)+4*l5
        const int lrow = (r & 3) + 8 * (r >> 2) + 4 * l5;
        lgs[lrow * 68 + g * 32 + l31] = acc[r];
    }
    __syncthreads();

    // ---- row epilogue: 4 threads per row, 16 experts each (verified R5+) --
    const int erow = t >> 2, q = t & 3;     // 32 rows x 4 lanes = 128 thr
    float L[16];
    #pragma unroll
    for (int i = 0; i < 4; ++i) {
        float4 v = *reinterpret_cast<const float4*>(lgs + erow * 68 + q * 16 + i * 4);
        L[4*i] = v.x; L[4*i+1] = v.y; L[4*i+2] = v.z; L[4*i+3] = v.w;
    }
    float v1 = -3.4e38f, v2 = -3.4e38f, v3 = -3.4e38f;
    int   e1 = 1 << 30,  e2 = 1 << 30,  e3 = 1 << 30;
    #pragma unroll
    for (int i = 0; i < 16; ++i) {
        float v = L[i]; int e = q * 16 + i;
        if      (gt_(v, e, v1, e1)) { v3=v2; e3=e2; v2=v1; e2=e1; v1=v; e1=e; }
        else if (gt_(v, e, v2, e2)) { v3=v2; e3=e2; v2=v; e2=e; }
        else if (gt_(v, e, v3, e3)) { v3=v; e3=e; }
    }
    #pragma unroll
    for (int m = 1; m <= 2; m <<= 1) {      // merge the row's 4 lanes
        float o1 = __shfl_xor(v1, m), o2 = __shfl_xor(v2, m), o3 = __shfl_xor(v3, m);
        int  oe1 = __shfl_xor(e1, m), oe2 = __shfl_xor(e2, m), oe3 = __shfl_xor(e3, m);
        float n1, n2, n3; int m1, m2, m3;
        if (gt_(v1, e1, o1, oe1)) {
            n1 = v1; m1 = e1;
            if (gt_(v2, e2, o1, oe1)) {
                n2 = v2; m2 = e2;
                if (gt_(v3, e3, o1, oe1)) { n3 = v3; m3 = e3; } else { n3 = o1; m3 = oe1; }
            } else {
                n2 = o1; m2 = oe1;
                if (gt_(v2, e2, o2, oe2)) { n3 = v2; m3 = e2; } else { n3 = o2; m3 = oe2; }
            }
        } else {
            n1 = o1; m1 = oe1;
            if (gt_(o2, oe2, v1, e1)) {
                n2 = o2; m2 = oe2;
                if (gt_(o3, oe3, v1, e1)) { n3 = o3; m3 = oe3; } else { n3 = v1; m3 = e1; }
            } else {
                n2 = v1; m2 = e1;
                if (gt_(o2, oe2, v2, e2)) { n3 = o2; m3 = oe2; } else { n3 = v2; m3 = e2; }
            }
        }
        v1 = n1; e1 = m1; v2 = n2; e2 = m2; v3 = n3; e3 = m3;
    }
    float pr[16], sl = 0.0f;
    #pragma unroll
    for (int i = 0; i < 16; ++i) { pr[i] = expf(L[i] - v1); sl += pr[i]; }
    float S = sl;
    S += __shfl_xor(S, 1); S += __shfl_xor(S, 2);
    const float invS = 1.0f / S;
    #pragma unroll
    for (int i = 0; i < 16; ++i) pr[i] *= invS;
    // per-expert partial sums across this wave's 16 rows
    #pragma unroll
    for (int m = 4; m <= 32; m <<= 1)
        #pragma unroll
        for (int i = 0; i < 16; ++i) pr[i] += __shfl_xor(pr[i], m);
    float* auxred = lgs + 32 * 68;          // 2 waves x 64 experts
    if (lane < 4) {
        #pragma unroll
        for (int i = 0; i < 16; ++i) auxred[g * 64 + q * 16 + i] = pr[i];
    }
    if (q == 0) {
        const float p1 = invS;              // exp(v1-v1)*invS
        const float p2 = expf(v2 - v1) * invS;
        const float dn = p1 + p2 + EPSF;
        const int r = row0 + erow;
        out[2 * r]                 = p1 / dn;
        out[2 * r + 1]             = p2 / dn;
        out[2 * NROWS + 2 * r]     = (float)e1;
        out[2 * NROWS + 2 * r + 1] = (float)e2;
        if (cap > 0 && (v1 - v2 < TAU || v2 - v3 < TAU)) {
            int pos = atomicAdd(cnt, 1);
            if (pos < cap) list[pos] = r;
        }
    }
    __syncthreads();
    if (t < 64) {
        float s = auxred[t] + auxred[64 + t];
        atomicAdd(&shard[(blockIdx.x & (NSHARD - 1)) * 64 + t], s);
    }
}

// ---------------------------------------------------------------------------
// Finalize: block 0 sums 8 aux shards -> aux loss; blocks 1..64 repair
// flagged rows with exact fp32 logits.
// ---------------------------------------------------------------------------
__global__ __launch_bounds__(256) void finalize_kernel(
    const float* __restrict__ x, const float* __restrict__ gw,
    float* __restrict__ out, const float* __restrict__ shard,
    const int* __restrict__ cnt, const int* __restrict__ list, int cap)
{
    if (blockIdx.x == 0) {
        const int tt = threadIdx.x;
        if (tt < 64) {
            float m = 0.0f;
            #pragma unroll
            for (int s = 0; s < NSHARD; ++s) m += shard[s * 64 + tt];
            m *= (1.0f / (float)NROWS);
            float v = m * logf(m + EPSF);
            #pragma unroll
            for (int k = 1; k <= 32; k <<= 1) v += __shfl_xor(v, k);
            if (tt == 0) out[4 * NROWS] = v;
        }
        return;
    }
    __shared__ float lg[64];
    const int n = (cap > 0) ? min(*cnt, cap) : 0;
    const int tt = threadIdx.x, e = tt >> 2, part = tt & 3;
    for (int j = (int)blockIdx.x - 1; j < n; j += 64) {
        const int row = list[j];
        const float* xrp = x  + (size_t)row * DDIM + part * 256;
        const float* wrp = gw + (size_t)e   * DDIM + part * 256;
        float a = 0.0f;
        #pragma unroll 8
        for (int kk = 0; kk < 64; ++kk) {
            float4 xv = *reinterpret_cast<const float4*>(xrp + kk * 4);
            float4 wv = *reinterpret_cast<const float4*>(wrp + kk * 4);
            a += xv.x * wv.x + xv.y * wv.y + xv.z * wv.z + xv.w * wv.w;
        }
        a += __shfl_xor(a, 1); a += __shfl_xor(a, 2);
        if (part == 0) lg[e] = a;
        __syncthreads();
        if (tt < 4) {
            const int q = tt;
            float v1 = -3.4e38f, v2 = -3.4e38f; int e1 = 1 << 30, e2 = 1 << 30;
            float Lr[16];
            #pragma unroll
            for (int i = 0; i < 16; ++i) {
                float v = Lr[i] = lg[q * 16 + i]; int ee = q * 16 + i;
                if      (gt_(v, ee, v1, e1)) { v2 = v1; e2 = e1; v1 = v; e1 = ee; }
                else if (gt_(v, ee, v2, e2)) { v2 = v; e2 = ee; }
            }
            #pragma unroll
            for (int m = 1; m <= 2; m <<= 1) {
                float o1 = __shfl_xor(v1, m), o2 = __shfl_xor(v2, m);
                int  oe1 = __shfl_xor(e1, m), oe2 = __shfl_xor(e2, m);
                float n1, n2; int m1, m2;
                if (gt_(v1, e1, o1, oe1)) {
                    n1 = v1; m1 = e1;
                    if (gt_(v2, e2, o1, oe1)) { n2 = v2; m2 = e2; } else { n2 = o1; m2 = oe1; }
                } else {
                    n1 = o1; m1 = oe1;
                    if (gt_(o2, oe2, v1, e1)) { n2 = o2; m2 = oe2; } else { n2 = v1; m2 = e1; }
                }
                v1 = n1; e1 = m1; v2 = n2; e2 = m2;
            }
            float s = 0.0f;
            #pragma unroll
            for (int i = 0; i < 16; ++i) s += expf(Lr[i] - v1);
            s += __shfl_xor(s, 1); s += __shfl_xor(s, 2);
            if (q == 0) {
                const float invS = 1.0f / s;
                const float p1 = invS, p2 = expf(v2 - v1) * invS;
                const float dn = p1 + p2 + EPSF;
                out[2 * row]                 = p1 / dn;
                out[2 * row + 1]             = p2 / dn;
                out[2 * NROWS + 2 * row]     = (float)e1;
                out[2 * NROWS + 2 * row + 1] = (float)e2;
            }
        }
        __syncthreads();
    }
}

extern "C" void kernel_launch(void* const* d_in, const int* in_sizes, int n_in,
                              void* d_out, int out_size, void* d_ws, size_t ws_size,
                              hipStream_t stream)
{
    const float* x  = (const float*)d_in[0];
    const float* gw = (const float*)d_in[1];
    float* out      = (float*)d_out;

    // d_ws layout: [wp 256KB][shard 2KB][cnt 4B pad->256B][list ...]
    unsigned short* wp = (unsigned short*)d_ws;
    float* shard   = (float*)((char*)d_ws + 262144);
    int*   cnt     = (int*)((char*)d_ws + 264192);
    int*   list    = (int*)((char*)d_ws + 264448);
    int cap = 0;
    if (ws_size >= 264448 + 4096) {
        size_t avail = (ws_size - 264448) / sizeof(int);
        cap = (avail > CAPMAX) ? CAPMAX : (int)avail;
    }

    hipLaunchKernelGGL(wpack_kernel, dim3(64), dim3(256), 0, stream,
                       gw, wp, shard, cnt);
    hipLaunchKernelGGL(moe_main, dim3(NROWS / 32), dim3(128), 32768, stream,
                       x, wp, out, shard, cnt, list, cap);
    hipLaunchKernelGGL(finalize_kernel, dim3(65), dim3(256), 0, stream,
                       x, gw, out, shard, cnt, list, cap);
}